// Round 14
// baseline (160.250 us; speedup 1.0000x reference)
//
#include <hip/hip_runtime.h>

// GCN layer, bucket-binned pull aggregation (register accumulate, no float atomics,
// no global int atomics):
//   binning (bucket = row>>7): chunked counting sort, NSPLIT=2 bucket-range split
//     (each block reads the whole chunk, handles half the buckets); binned[]
//     packed (row&127)<<25 | col; FIXED CAP=4096 -> bucket base = b*CAP.
//     scanB1 FUSED into scatC: each block sums blkhist[i<c][k] itself (<=97
//     coalesced 1.5KB reads, L2-fed); last-chunk blocks emit btotal.
//   distrans: one block per bucket (=128-node tile): LDS row-hist -> dis + lrp, then
//     MFMA bf16 GEMM transform (16x16x32, K 48 padded to 64, 8 waves x 16 rows);
//     writes zp rows of 64 bf16 (128 B aligned lines, features 48..63 zeroed)
//   aggregate: one block (512 thr) per bucket; LDS counting-sort by row (lrp
//     precomputed, col addrs pre-multiplied x32); MASKED unroll-4 gather,
//     fused dis*acc+bias+ReLU.
// History: global atomics dead 3 ways (R1/R6 float, R4 LDS float, R12 int deg[]
//   cross-XCD ping-pong 236us). R16 grid.sync fusion REGRESSED 754us. R17 RB=128
//   = 151.9. R18 RB=256 REGRESSED (aggregate @29% occ; not occupancy-bound per
//   R20 too). R21 masked unroll-4 = 149.8 (gather MLP sweet spot 4; unroll-8
//   REGRESSED R22). R23 NSPLIT=2 = 146.2 BEST. R24 CHUNK=32K/NSPLIT=4 REGRESSED
//   151.2: per-block READ window is CHUNK, not CHUNK/NSPLIT -- redundant read
//   traffic doubled (+38MB ~ +5us). CHUNK=16384/NSPLIT=2 is the family optimum.
// R25: R23 exact + scanB1 fused into scatC (5 -> 4 kernels; prefix summed
//   in-block, value-identical cur/btotal -> bit-identical binned & output).

#define NF 48
#define NPAIR 24           // NF/2 valid uints per node row in zp
#define ZLD 32             // zp row stride in uints (128 B aligned)
#define RB 128             // rows per bucket
#define RSH 25             // row field shift in packed entry
#define CMASK 0x1ffffffu   // col mask (25 bits; col < 2^17)
#define CHUNK 16384        // edges per binning chunk (98 chunks)
#define CAP 4096           // fixed per-bucket capacity in binned[] (mean 2046)
#define SCOL_CAP 4096      // per-bucket LDS col capacity (16 KB)
#define NSPLIT 2           // bucket-range split of the binning kernels

typedef __attribute__((ext_vector_type(8))) short frag_ab;   // 8 bf16
typedef __attribute__((ext_vector_type(4))) float f32x4;

__device__ inline unsigned short f2bf(float f) {
    unsigned u = __float_as_uint(f);
    u = (u + 0x7fffu + ((u >> 16) & 1u)) >> 16;   // RN-even
    return (unsigned short)u;
}

// Pass A: per-chunk bucket histogram, bucket-range split; blkhist[chunk][bucket]
__global__ void histA_kernel(const int* __restrict__ row, int* __restrict__ blkhist,
                             int NBUK, int SL, int E) {
    extern __shared__ int hist[];       // SL ints
    const int b  = blockIdx.x / NSPLIT;
    const int sp = blockIdx.x % NSPLIT;
    const int klo = sp * SL;
    const int khi = min(NBUK, klo + SL);
    for (int i = threadIdx.x; i < SL; i += blockDim.x) hist[i] = 0;
    __syncthreads();
    int s = b * CHUNK, t = min(E, s + CHUNK);
    int nv = (t - s) >> 2;              // int4 groups
    const int4* r4 = (const int4*)(row + s);
    for (int i = threadIdx.x; i < nv; i += blockDim.x) {
        int4 r = r4[i];
        int k0 = r.x >> 7; if (k0 >= klo && k0 < khi) atomicAdd(&hist[k0 - klo], 1);
        int k1 = r.y >> 7; if (k1 >= klo && k1 < khi) atomicAdd(&hist[k1 - klo], 1);
        int k2 = r.z >> 7; if (k2 >= klo && k2 < khi) atomicAdd(&hist[k2 - klo], 1);
        int k3 = r.w >> 7; if (k3 >= klo && k3 < khi) atomicAdd(&hist[k3 - klo], 1);
    }
    for (int e = s + nv * 4 + threadIdx.x; e < t; e += blockDim.x) {
        int k0 = row[e] >> 7;
        if (k0 >= klo && k0 < khi) atomicAdd(&hist[k0 - klo], 1);
    }
    __syncthreads();
    int* dst = blkhist + (size_t)b * NBUK;
    for (int k = klo + threadIdx.x; k < khi; k += blockDim.x) dst[k] = hist[k - klo];
}

// Pass C (scanB1 fused): per block, compute chunk-prefix per bucket from blkhist,
// then scatter to fixed-CAP regions; last-chunk blocks emit btotal.
// Packed (row&127)<<25 | col. Overflow-guarded (drop, stay in-bounds).
__global__ void scatC_kernel(const int* __restrict__ row, const int* __restrict__ col,
                             const int* __restrict__ blkhist, int* __restrict__ btotal,
                             unsigned* __restrict__ binned, int NBUK, int SL,
                             int NCH, int E) {
    extern __shared__ int cur[];        // SL ints
    const int b  = blockIdx.x / NSPLIT;
    const int sp = blockIdx.x % NSPLIT;
    const int klo = sp * SL;
    const int khi = min(NBUK, klo + SL);
    // prefix over chunks i<b for each bucket in slice (coalesced per iteration)
    for (int k = klo + threadIdx.x; k < khi; k += blockDim.x) {
        int acc = 0;
        for (int i = 0; i < b; i++) acc += blkhist[(size_t)i * NBUK + k];
        cur[k - klo] = k * CAP + acc;
        if (b == NCH - 1)
            btotal[k] = acc + blkhist[(size_t)b * NBUK + k];
    }
    __syncthreads();
    int s = b * CHUNK, t = min(E, s + CHUNK);
    int nv = (t - s) >> 2;
    const int4* r4 = (const int4*)(row + s);
    const int4* c4 = (const int4*)(col + s);
    for (int i = threadIdx.x; i < nv; i += blockDim.x) {
        int4 r = r4[i];
        int4 c = c4[i];
        int k0 = r.x >> 7;
        if (k0 >= klo && k0 < khi) {
            int p = atomicAdd(&cur[k0 - klo], 1);
            if (p < (k0 + 1) * CAP)
                binned[p] = ((unsigned)(r.x & (RB - 1)) << RSH) | (unsigned)c.x;
        }
        int k1 = r.y >> 7;
        if (k1 >= klo && k1 < khi) {
            int p = atomicAdd(&cur[k1 - klo], 1);
            if (p < (k1 + 1) * CAP)
                binned[p] = ((unsigned)(r.y & (RB - 1)) << RSH) | (unsigned)c.y;
        }
        int k2 = r.z >> 7;
        if (k2 >= klo && k2 < khi) {
            int p = atomicAdd(&cur[k2 - klo], 1);
            if (p < (k2 + 1) * CAP)
                binned[p] = ((unsigned)(r.z & (RB - 1)) << RSH) | (unsigned)c.z;
        }
        int k3 = r.w >> 7;
        if (k3 >= klo && k3 < khi) {
            int p = atomicAdd(&cur[k3 - klo], 1);
            if (p < (k3 + 1) * CAP)
                binned[p] = ((unsigned)(r.w & (RB - 1)) << RSH) | (unsigned)c.w;
        }
    }
    for (int e = s + nv * 4 + threadIdx.x; e < t; e += blockDim.x) {
        int r = row[e], c = col[e];
        int k0 = r >> 7;
        if (k0 >= klo && k0 < khi) {
            int p = atomicAdd(&cur[k0 - klo], 1);
            if (p < (k0 + 1) * CAP)
                binned[p] = ((unsigned)(r & (RB - 1)) << RSH) | (unsigned)c;
        }
    }
}

// Fused degdis + transform. One block (512 thr) per bucket b == 128-node tile b.
// Phase 1 (all 512): LDS row-hist of binned bucket -> lrp_g, dis (global + LDS).
// Phase 2: stage x,W -> bf16 LDS; all 8 waves MFMA 16 rows each; fused dis scale.
__global__ __launch_bounds__(512)
void distrans_kernel(const int* __restrict__ btotal, const unsigned* __restrict__ binned,
                     const float* __restrict__ x, const float* __restrict__ W,
                     float* __restrict__ dis, int* __restrict__ lrp_g,
                     unsigned short* __restrict__ zp16, int N) {
    __shared__ int hist[RB];
    __shared__ float disS[RB];
    __shared__ unsigned short Xb[RB * 64];   // 16 KB, row stride 64 (K padded)
    __shared__ unsigned short Wb[48 * 64];   // 6 KB, [out][in] = B[k][n] source
    const int b = blockIdx.x;
    const int tid = threadIdx.x;
    const int nb0 = b * RB;
    const int s = b * CAP;
    const int t = s + min(btotal[b], CAP);

    if (tid < RB) hist[tid] = 0;
    __syncthreads();
    for (int e = s + tid; e < t; e += 512)
        atomicAdd(&hist[binned[e] >> RSH], 1);

    // stage x -> Xb (bf16), 1536 float4s (independent of hist; overlaps atomics)
    const float4* x4 = (const float4*)x;
    for (int i = tid; i < RB * 12; i += 512) {
        int r = i / 12, c = i % 12;
        int n = nb0 + r;
        float4 v = (n < N) ? x4[(size_t)n * 12 + c] : make_float4(0.f, 0.f, 0.f, 0.f);
        unsigned short* d = &Xb[r * 64 + c * 4];
        d[0] = f2bf(v.x); d[1] = f2bf(v.y); d[2] = f2bf(v.z); d[3] = f2bf(v.w);
    }
    // zero Xb K-pad (cols 48..63): rows*8 uints
    for (int i = tid; i < RB * 8; i += 512)
        ((unsigned*)Xb)[(i >> 3) * 32 + 24 + (i & 7)] = 0u;
    // stage W -> Wb (bf16), 576 float4s
    const float4* W4 = (const float4*)W;
    for (int i = tid; i < 576; i += 512) {
        int r = i / 12, c = i % 12;
        float4 v = W4[r * 12 + c];
        unsigned short* d = &Wb[r * 64 + c * 4];
        d[0] = f2bf(v.x); d[1] = f2bf(v.y); d[2] = f2bf(v.z); d[3] = f2bf(v.w);
    }
    for (int i = tid; i < 48 * 8; i += 512)
        ((unsigned*)Wb)[(i >> 3) * 32 + 24 + (i & 7)] = 0u;
    __syncthreads();

    // row scan (128 entries, one wave, two 64-passes with carry) -> lrp_g, dis
    if (tid < 64) {
        int* lp = lrp_g + (size_t)b * (RB + 1);
        int carry = 0;
        for (int base = 0; base < RB; base += 64) {
            int i = base + tid;
            int v = hist[i];
            int incl = v;
            #pragma unroll
            for (int off = 1; off < 64; off <<= 1) {
                int u = __shfl_up(incl, off, 64);
                if (tid >= off) incl += u;
            }
            lp[i] = carry + incl - v;
            float dv = (v > 0) ? rsqrtf((float)v) : 0.0f;
            disS[i] = dv;
            int n = nb0 + i;
            if (n < N) dis[n] = dv;
            carry += __shfl(incl, 63, 64);
        }
        if (tid == 0) lp[RB] = carry;
    }
    __syncthreads();

    // all 8 waves: wave wv handles rows [wv*16, wv*16+16)
    const int wv = tid >> 6, lane = tid & 63;
    const int quad = lane >> 4, l16 = lane & 15;
    const int mrow = wv * 16 + l16;

    frag_ab A0 = *(const frag_ab*)&Xb[mrow * 64 + quad * 8];
    frag_ab A1 = *(const frag_ab*)&Xb[mrow * 64 + 32 + quad * 8];
    f32x4 acc[3];
#pragma unroll
    for (int tt = 0; tt < 3; tt++) {
        frag_ab B0 = *(const frag_ab*)&Wb[(tt * 16 + l16) * 64 + quad * 8];
        frag_ab B1 = *(const frag_ab*)&Wb[(tt * 16 + l16) * 64 + 32 + quad * 8];
        f32x4 z = {0.f, 0.f, 0.f, 0.f};
        z = __builtin_amdgcn_mfma_f32_16x16x32_bf16(A0, B0, z, 0, 0, 0);
        z = __builtin_amdgcn_mfma_f32_16x16x32_bf16(A1, B1, z, 0, 0, 0);
        acc[tt] = z;
    }
    // D mapping: col = lane&15 (feature within tile), row = quad*4 + r (node)
#pragma unroll
    for (int r = 0; r < 4; r++) {
        int lrow = wv * 16 + quad * 4 + r;
        int n = nb0 + lrow;
        if (n < N) {
            float dn = disS[lrow];
            unsigned short* zr = zp16 + (size_t)n * (2 * ZLD);
#pragma unroll
            for (int tt = 0; tt < 3; tt++)
                zr[tt * 16 + l16] = f2bf(dn * acc[tt][r]);
            zr[48 + l16] = 0;            // feature pad -> full-line writes
        }
    }
}

// One block (512 thr) per bucket: LDS counting sort by row (cols pre-multiplied x32),
// masked unroll-4 gather (4 independent loads per iteration, no serial tail),
// fused dis*acc+bias+ReLU epilogue.
__global__ __launch_bounds__(512, 8)
void aggregate_kernel(const int* __restrict__ btotal, const unsigned* __restrict__ binned,
                      const int* __restrict__ lrp_g,
                      const unsigned* __restrict__ zp, const float* __restrict__ dis,
                      const float* __restrict__ bias, float* __restrict__ out, int N) {
    __shared__ int scol[SCOL_CAP];       // 16 KB
    __shared__ int lrp[RB + 1];
    __shared__ int cur[RB];
    const int b = blockIdx.x;
    const int s = b * CAP;
    const int cnt = btotal[b];
    const int t = s + min(cnt, CAP);
    const int tid = threadIdx.x;
    if (tid < RB + 1) {
        int v = lrp_g[(size_t)b * (RB + 1) + tid];
        lrp[tid] = v;
        if (tid < RB) cur[tid] = v;
    }
    __syncthreads();
    const bool sorted = (cnt <= SCOL_CAP);
    if (sorted) {
        for (int e = s + tid; e < t; e += 512) {
            unsigned rc = binned[e];
            int pos = atomicAdd(&cur[rc >> RSH], 1);
            scol[pos] = (int)((rc & CMASK) << 5);   // pre-mult x32 (ZLD)
        }
    }
    __syncthreads();

    const int lane = tid & 63;
    const int wave = tid >> 6;           // 0..7
    const int h = lane >> 5;             // half-wave: edge parity
    const int j = lane & 31;             // feature-pair index (24..31 = pad lanes)
    const bool act = (j < NPAIR);
    const int ja = act ? j : 0;          // inactive lanes alias lane-0's word
    float bb0 = 0.0f, bb1 = 0.0f;
    if (act) { bb0 = bias[2 * j]; bb1 = bias[2 * j + 1]; }
    const int rbase = b * RB;
    for (int ri = wave; ri < RB; ri += 8) {
        int r = rbase + ri;
        if (r >= N) break;
        float a0 = 0.0f, a1 = 0.0f;
        if (sorted) {
            int ks = lrp[ri], ke = lrp[ri + 1];
            // masked unroll-4: always 4 independent loads; validity selects are
            // lane-uniform (k,ke uniform); clamped indices stay on valid entries
            // (k < ke on loop entry), so masked slots read finite zp words.
            for (int k = ks + h; k < ke; k += 8) {
                int k1 = k + 2, k2 = k + 4, k3 = k + 6;
                bool v1 = k1 < ke, v2 = k2 < ke, v3 = k3 < ke;
                int c0 = scol[k];
                int c1 = scol[v1 ? k1 : k];
                int c2 = scol[v2 ? k2 : k];
                int c3 = scol[v3 ? k3 : k];
                unsigned u0 = zp[(size_t)c0 + ja];   // aligned 1-line rows
                unsigned u1 = zp[(size_t)c1 + ja];
                unsigned u2 = zp[(size_t)c2 + ja];
                unsigned u3 = zp[(size_t)c3 + ja];
                float f00 = __uint_as_float(u0 << 16);
                float f01 = v1 ? __uint_as_float(u1 << 16) : 0.0f;
                float f02 = v2 ? __uint_as_float(u2 << 16) : 0.0f;
                float f03 = v3 ? __uint_as_float(u3 << 16) : 0.0f;
                a0 += (f00 + f01) + (f02 + f03);
                float f10 = __uint_as_float(u0 & 0xffff0000u);
                float f11 = v1 ? __uint_as_float(u1 & 0xffff0000u) : 0.0f;
                float f12 = v2 ? __uint_as_float(u2 & 0xffff0000u) : 0.0f;
                float f13 = v3 ? __uint_as_float(u3 & 0xffff0000u) : 0.0f;
                a1 += (f10 + f11) + (f12 + f13);
            }
        } else {                         // overflow fallback (statistically unreachable)
            for (int e = s; e < t; e++) {
                unsigned rc = binned[e];
                if ((int)(rc >> RSH) == ri && h == 0 && act) {
                    unsigned u0 = zp[((size_t)(rc & CMASK) << 5) + ja];
                    a0 += __uint_as_float(u0 << 16);
                    a1 += __uint_as_float(u0 & 0xffff0000u);
                }
            }
        }
        a0 += __shfl_xor(a0, 32, 64);    // combine edge parities
        a1 += __shfl_xor(a1, 32, 64);
        if (h == 0 && act) {
            float dr = dis[r];
            float v0 = dr * a0 + bb0;
            float v1 = dr * a1 + bb1;
            float2 o;
            o.x = v0 > 0.0f ? v0 : 0.0f;
            o.y = v1 > 0.0f ? v1 : 0.0f;
            *(float2*)(out + (size_t)r * NF + 2 * j) = o;
        }
    }
}

extern "C" void kernel_launch(void* const* d_in, const int* in_sizes, int n_in,
                              void* d_out, int out_size, void* d_ws, size_t ws_size,
                              hipStream_t stream) {
    const float* x    = (const float*)d_in[0];
    const int*   ei   = (const int*)d_in[1];
    const float* W    = (const float*)d_in[2];
    const float* bias = (const float*)d_in[3];
    float* out = (float*)d_out;

    const int N = in_sizes[0] / NF;
    const int E = in_sizes[1] / 2;
    const int* row = ei;                      // edge_index[0]
    const int* col = ei + E;                  // edge_index[1]
    const int NBUK = (N + RB - 1) / RB;       // 782
    const int NCH  = (E + CHUNK - 1) / CHUNK; // 98
    const int SL   = (NBUK + NSPLIT - 1) / NSPLIT;   // bucket-slice length (391)

    // workspace layout
    char* ws = (char*)d_ws;
    unsigned* zp      = (unsigned*)ws;       ws += (size_t)N * ZLD * 4;          // 12.8 MB
    unsigned* binned  = (unsigned*)ws;       ws += (size_t)NBUK * CAP * 4;       // 12.8 MB
    float*    dis     = (float*)ws;          ws += (size_t)N * 4;
    int*      blkhist = (int*)ws;            ws += (size_t)NCH * NBUK * 4;       // 306 KB
    int*      btotal  = (int*)ws;            ws += (size_t)NBUK * 4;
    int*      lrp_g   = (int*)ws;            ws += (size_t)NBUK * (RB + 1) * 4;  // 403 KB

    histA_kernel<<<NCH * NSPLIT, 512, SL * 4, stream>>>(row, blkhist, NBUK, SL, E);
    scatC_kernel<<<NCH * NSPLIT, 512, SL * 4, stream>>>(row, col, blkhist, btotal,
                                                        binned, NBUK, SL, NCH, E);
    distrans_kernel<<<NBUK, 512, 0, stream>>>(btotal, binned, x, W, dis, lrp_g,
                                              (unsigned short*)zp, N);
    aggregate_kernel<<<NBUK, 512, 0, stream>>>(btotal, binned, lrp_g, zp, dis, bias, out, N);
}

// Round 15
// 144.665 us; speedup vs baseline: 1.1077x; 1.1077x over previous
//
#include <hip/hip_runtime.h>

// GCN layer, bucket-binned pull aggregation (register accumulate, no float atomics,
// no global int atomics):
//   binning (bucket = row>>7): chunked counting sort, NSPLIT=2 bucket-range split;
//     binned[] packed (row&127)<<25 | col; FIXED CAP=4096 -> bucket base = b*CAP;
//     separate scanB1 (R25 taught: fusing prefix into scatC = O(NCH^2) strided
//     reads, +14us -- keep the cheap 782-block scan kernel).
//   distrans: one block per bucket (=128-node tile): LDS row-hist -> dis + lrp, then
//     MFMA bf16 GEMM transform (16x16x32, K 48 padded to 64, 8 waves x 16 rows);
//     writes zp rows of 64 bf16 (128 B aligned lines, features 48..63 zeroed)
//   aggregate: one block (512 thr) per bucket; LDS counting-sort by row; DUAL-ROW
//     masked unroll-4 gather: each wave works rows (ri, ri+8) concurrently ->
//     8 real in-flight line loads (no masked-issue waste), single-row tails;
//     fused dis*acc+bias+ReLU.
// History: global atomics dead 3 ways (R1/R6/R4/R12). R16 grid.sync fusion 754us.
//   R17 RB=128 = 151.9. R18/R20: aggregate NOT occupancy-bound. R21 masked
//   unroll-4 = 149.8 (MLP lever works). R22 unroll-8 REGRESSED (masked slots
//   waste VMEM issue on short rows). R23 NSPLIT=2 = 146.2 BEST. R24 CHUNK=32K
//   REGRESSED (per-block read window is CHUNK; redundant reads doubled). R25
//   scanB1-fusion REGRESSED 160.2 (O(NCH^2) strided prefix per block).
// R26: R23 exact + dual-row gather (MLP 4->8 real loads during combined phase;
//   per-row accumulation order unchanged -> bit-identical output).

#define NF 48
#define NPAIR 24           // NF/2 valid uints per node row in zp
#define ZLD 32             // zp row stride in uints (128 B aligned)
#define RB 128             // rows per bucket
#define RSH 25             // row field shift in packed entry
#define CMASK 0x1ffffffu   // col mask (25 bits; col < 2^17)
#define CHUNK 16384        // edges per binning chunk (98 chunks)
#define CAP 4096           // fixed per-bucket capacity in binned[] (mean 2046)
#define SCOL_CAP 4096      // per-bucket LDS col capacity (16 KB)
#define NSPLIT 2           // bucket-range split of the binning kernels

typedef __attribute__((ext_vector_type(8))) short frag_ab;   // 8 bf16
typedef __attribute__((ext_vector_type(4))) float f32x4;

__device__ inline unsigned short f2bf(float f) {
    unsigned u = __float_as_uint(f);
    u = (u + 0x7fffu + ((u >> 16) & 1u)) >> 16;   // RN-even
    return (unsigned short)u;
}

// Pass A: per-chunk bucket histogram, bucket-range split; blkhist[chunk][bucket]
__global__ void histA_kernel(const int* __restrict__ row, int* __restrict__ blkhist,
                             int NBUK, int SL, int E) {
    extern __shared__ int hist[];       // SL ints
    const int b  = blockIdx.x / NSPLIT;
    const int sp = blockIdx.x % NSPLIT;
    const int klo = sp * SL;
    const int khi = min(NBUK, klo + SL);
    for (int i = threadIdx.x; i < SL; i += blockDim.x) hist[i] = 0;
    __syncthreads();
    int s = b * CHUNK, t = min(E, s + CHUNK);
    int nv = (t - s) >> 2;              // int4 groups
    const int4* r4 = (const int4*)(row + s);
    for (int i = threadIdx.x; i < nv; i += blockDim.x) {
        int4 r = r4[i];
        int k0 = r.x >> 7; if (k0 >= klo && k0 < khi) atomicAdd(&hist[k0 - klo], 1);
        int k1 = r.y >> 7; if (k1 >= klo && k1 < khi) atomicAdd(&hist[k1 - klo], 1);
        int k2 = r.z >> 7; if (k2 >= klo && k2 < khi) atomicAdd(&hist[k2 - klo], 1);
        int k3 = r.w >> 7; if (k3 >= klo && k3 < khi) atomicAdd(&hist[k3 - klo], 1);
    }
    for (int e = s + nv * 4 + threadIdx.x; e < t; e += blockDim.x) {
        int k0 = row[e] >> 7;
        if (k0 >= klo && k0 < khi) atomicAdd(&hist[k0 - klo], 1);
    }
    __syncthreads();
    int* dst = blkhist + (size_t)b * NBUK;
    for (int k = klo + threadIdx.x; k < khi; k += blockDim.x) dst[k] = hist[k - klo];
}

// Pass B: per bucket, exclusive scan over chunks (in place, strided) + total.
// Bucket base in binned[] is b*CAP by construction (no cross-bucket scan).
__global__ void scanB1_kernel(int* __restrict__ blkhist, int* __restrict__ btotal,
                              int NBUK, int NCH) {
    int k = blockIdx.x;
    int lane = threadIdx.x;             // blockDim.x == 64
    int carry = 0;
    for (int base = 0; base < NCH; base += 64) {
        int i = base + lane;
        int v = (i < NCH) ? blkhist[(size_t)i * NBUK + k] : 0;
        int incl = v;
        #pragma unroll
        for (int off = 1; off < 64; off <<= 1) {
            int u = __shfl_up(incl, off, 64);
            if (lane >= off) incl += u;
        }
        if (i < NCH) blkhist[(size_t)i * NBUK + k] = carry + incl - v;
        carry += __shfl(incl, 63, 64);
    }
    if (lane == 0) btotal[k] = carry;
}

// Pass C: scatter to fixed-CAP bucket regions, bucket-range split; packed
// (row&127)<<25 | col. Overflow-guarded (drop, stay in-bounds).
__global__ void scatC_kernel(const int* __restrict__ row, const int* __restrict__ col,
                             const int* __restrict__ blkhist,
                             unsigned* __restrict__ binned, int NBUK, int SL, int E) {
    extern __shared__ int cur[];        // SL ints
    const int b  = blockIdx.x / NSPLIT;
    const int sp = blockIdx.x % NSPLIT;
    const int klo = sp * SL;
    const int khi = min(NBUK, klo + SL);
    const int* boff = blkhist + (size_t)b * NBUK;
    for (int k = klo + threadIdx.x; k < khi; k += blockDim.x)
        cur[k - klo] = k * CAP + boff[k];    // coalesced
    __syncthreads();
    int s = b * CHUNK, t = min(E, s + CHUNK);
    int nv = (t - s) >> 2;
    const int4* r4 = (const int4*)(row + s);
    const int4* c4 = (const int4*)(col + s);
    for (int i = threadIdx.x; i < nv; i += blockDim.x) {
        int4 r = r4[i];
        int4 c = c4[i];
        int k0 = r.x >> 7;
        if (k0 >= klo && k0 < khi) {
            int p = atomicAdd(&cur[k0 - klo], 1);
            if (p < (k0 + 1) * CAP)
                binned[p] = ((unsigned)(r.x & (RB - 1)) << RSH) | (unsigned)c.x;
        }
        int k1 = r.y >> 7;
        if (k1 >= klo && k1 < khi) {
            int p = atomicAdd(&cur[k1 - klo], 1);
            if (p < (k1 + 1) * CAP)
                binned[p] = ((unsigned)(r.y & (RB - 1)) << RSH) | (unsigned)c.y;
        }
        int k2 = r.z >> 7;
        if (k2 >= klo && k2 < khi) {
            int p = atomicAdd(&cur[k2 - klo], 1);
            if (p < (k2 + 1) * CAP)
                binned[p] = ((unsigned)(r.z & (RB - 1)) << RSH) | (unsigned)c.z;
        }
        int k3 = r.w >> 7;
        if (k3 >= klo && k3 < khi) {
            int p = atomicAdd(&cur[k3 - klo], 1);
            if (p < (k3 + 1) * CAP)
                binned[p] = ((unsigned)(r.w & (RB - 1)) << RSH) | (unsigned)c.w;
        }
    }
    for (int e = s + nv * 4 + threadIdx.x; e < t; e += blockDim.x) {
        int r = row[e], c = col[e];
        int k0 = r >> 7;
        if (k0 >= klo && k0 < khi) {
            int p = atomicAdd(&cur[k0 - klo], 1);
            if (p < (k0 + 1) * CAP)
                binned[p] = ((unsigned)(r & (RB - 1)) << RSH) | (unsigned)c;
        }
    }
}

// Fused degdis + transform. One block (512 thr) per bucket b == 128-node tile b.
// Phase 1 (all 512): LDS row-hist of binned bucket -> lrp_g, dis (global + LDS).
// Phase 2: stage x,W -> bf16 LDS; all 8 waves MFMA 16 rows each; fused dis scale.
__global__ __launch_bounds__(512)
void distrans_kernel(const int* __restrict__ btotal, const unsigned* __restrict__ binned,
                     const float* __restrict__ x, const float* __restrict__ W,
                     float* __restrict__ dis, int* __restrict__ lrp_g,
                     unsigned short* __restrict__ zp16, int N) {
    __shared__ int hist[RB];
    __shared__ float disS[RB];
    __shared__ unsigned short Xb[RB * 64];   // 16 KB, row stride 64 (K padded)
    __shared__ unsigned short Wb[48 * 64];   // 6 KB, [out][in] = B[k][n] source
    const int b = blockIdx.x;
    const int tid = threadIdx.x;
    const int nb0 = b * RB;
    const int s = b * CAP;
    const int t = s + min(btotal[b], CAP);

    if (tid < RB) hist[tid] = 0;
    __syncthreads();
    for (int e = s + tid; e < t; e += 512)
        atomicAdd(&hist[binned[e] >> RSH], 1);

    // stage x -> Xb (bf16), 1536 float4s (independent of hist; overlaps atomics)
    const float4* x4 = (const float4*)x;
    for (int i = tid; i < RB * 12; i += 512) {
        int r = i / 12, c = i % 12;
        int n = nb0 + r;
        float4 v = (n < N) ? x4[(size_t)n * 12 + c] : make_float4(0.f, 0.f, 0.f, 0.f);
        unsigned short* d = &Xb[r * 64 + c * 4];
        d[0] = f2bf(v.x); d[1] = f2bf(v.y); d[2] = f2bf(v.z); d[3] = f2bf(v.w);
    }
    // zero Xb K-pad (cols 48..63): rows*8 uints
    for (int i = tid; i < RB * 8; i += 512)
        ((unsigned*)Xb)[(i >> 3) * 32 + 24 + (i & 7)] = 0u;
    // stage W -> Wb (bf16), 576 float4s
    const float4* W4 = (const float4*)W;
    for (int i = tid; i < 576; i += 512) {
        int r = i / 12, c = i % 12;
        float4 v = W4[r * 12 + c];
        unsigned short* d = &Wb[r * 64 + c * 4];
        d[0] = f2bf(v.x); d[1] = f2bf(v.y); d[2] = f2bf(v.z); d[3] = f2bf(v.w);
    }
    for (int i = tid; i < 48 * 8; i += 512)
        ((unsigned*)Wb)[(i >> 3) * 32 + 24 + (i & 7)] = 0u;
    __syncthreads();

    // row scan (128 entries, one wave, two 64-passes with carry) -> lrp_g, dis
    if (tid < 64) {
        int* lp = lrp_g + (size_t)b * (RB + 1);
        int carry = 0;
        for (int base = 0; base < RB; base += 64) {
            int i = base + tid;
            int v = hist[i];
            int incl = v;
            #pragma unroll
            for (int off = 1; off < 64; off <<= 1) {
                int u = __shfl_up(incl, off, 64);
                if (tid >= off) incl += u;
            }
            lp[i] = carry + incl - v;
            float dv = (v > 0) ? rsqrtf((float)v) : 0.0f;
            disS[i] = dv;
            int n = nb0 + i;
            if (n < N) dis[n] = dv;
            carry += __shfl(incl, 63, 64);
        }
        if (tid == 0) lp[RB] = carry;
    }
    __syncthreads();

    // all 8 waves: wave wv handles rows [wv*16, wv*16+16)
    const int wv = tid >> 6, lane = tid & 63;
    const int quad = lane >> 4, l16 = lane & 15;
    const int mrow = wv * 16 + l16;

    frag_ab A0 = *(const frag_ab*)&Xb[mrow * 64 + quad * 8];
    frag_ab A1 = *(const frag_ab*)&Xb[mrow * 64 + 32 + quad * 8];
    f32x4 acc[3];
#pragma unroll
    for (int tt = 0; tt < 3; tt++) {
        frag_ab B0 = *(const frag_ab*)&Wb[(tt * 16 + l16) * 64 + quad * 8];
        frag_ab B1 = *(const frag_ab*)&Wb[(tt * 16 + l16) * 64 + 32 + quad * 8];
        f32x4 z = {0.f, 0.f, 0.f, 0.f};
        z = __builtin_amdgcn_mfma_f32_16x16x32_bf16(A0, B0, z, 0, 0, 0);
        z = __builtin_amdgcn_mfma_f32_16x16x32_bf16(A1, B1, z, 0, 0, 0);
        acc[tt] = z;
    }
    // D mapping: col = lane&15 (feature within tile), row = quad*4 + r (node)
#pragma unroll
    for (int r = 0; r < 4; r++) {
        int lrow = wv * 16 + quad * 4 + r;
        int n = nb0 + lrow;
        if (n < N) {
            float dn = disS[lrow];
            unsigned short* zr = zp16 + (size_t)n * (2 * ZLD);
#pragma unroll
            for (int tt = 0; tt < 3; tt++)
                zr[tt * 16 + l16] = f2bf(dn * acc[tt][r]);
            zr[48 + l16] = 0;            // feature pad -> full-line writes
        }
    }
}

// 4 masked independent loads for one row; accumulation order == R21.
#define GATHER4(KV, KE, A0, A1)                                             \
    {                                                                       \
        int k1_ = (KV) + 2, k2_ = (KV) + 4, k3_ = (KV) + 6;                 \
        bool v1_ = k1_ < (KE), v2_ = k2_ < (KE), v3_ = k3_ < (KE);          \
        int c0_ = scol[(KV)];                                               \
        int c1_ = scol[v1_ ? k1_ : (KV)];                                   \
        int c2_ = scol[v2_ ? k2_ : (KV)];                                   \
        int c3_ = scol[v3_ ? k3_ : (KV)];                                   \
        unsigned u0_ = zp[(size_t)c0_ + ja];                                \
        unsigned u1_ = zp[(size_t)c1_ + ja];                                \
        unsigned u2_ = zp[(size_t)c2_ + ja];                                \
        unsigned u3_ = zp[(size_t)c3_ + ja];                                \
        float f00_ = __uint_as_float(u0_ << 16);                            \
        float f01_ = v1_ ? __uint_as_float(u1_ << 16) : 0.0f;               \
        float f02_ = v2_ ? __uint_as_float(u2_ << 16) : 0.0f;               \
        float f03_ = v3_ ? __uint_as_float(u3_ << 16) : 0.0f;               \
        (A0) += (f00_ + f01_) + (f02_ + f03_);                              \
        float f10_ = __uint_as_float(u0_ & 0xffff0000u);                    \
        float f11_ = v1_ ? __uint_as_float(u1_ & 0xffff0000u) : 0.0f;       \
        float f12_ = v2_ ? __uint_as_float(u2_ & 0xffff0000u) : 0.0f;       \
        float f13_ = v3_ ? __uint_as_float(u3_ & 0xffff0000u) : 0.0f;       \
        (A1) += (f10_ + f11_) + (f12_ + f13_);                              \
    }

// One block (512 thr) per bucket: LDS counting sort by row (cols pre-multiplied x32),
// DUAL-ROW masked unroll-4 gather (8 real in-flight loads while both rows active),
// fused dis*acc+bias+ReLU epilogue.
__global__ __launch_bounds__(512, 8)
void aggregate_kernel(const int* __restrict__ btotal, const unsigned* __restrict__ binned,
                      const int* __restrict__ lrp_g,
                      const unsigned* __restrict__ zp, const float* __restrict__ dis,
                      const float* __restrict__ bias, float* __restrict__ out, int N) {
    __shared__ int scol[SCOL_CAP];       // 16 KB
    __shared__ int lrp[RB + 1];
    __shared__ int cur[RB];
    const int b = blockIdx.x;
    const int s = b * CAP;
    const int cnt = btotal[b];
    const int t = s + min(cnt, CAP);
    const int tid = threadIdx.x;
    if (tid < RB + 1) {
        int v = lrp_g[(size_t)b * (RB + 1) + tid];
        lrp[tid] = v;
        if (tid < RB) cur[tid] = v;
    }
    __syncthreads();
    const bool sorted = (cnt <= SCOL_CAP);
    if (sorted) {
        for (int e = s + tid; e < t; e += 512) {
            unsigned rc = binned[e];
            int pos = atomicAdd(&cur[rc >> RSH], 1);
            scol[pos] = (int)((rc & CMASK) << 5);   // pre-mult x32 (ZLD)
        }
    }
    __syncthreads();

    const int lane = tid & 63;
    const int wave = tid >> 6;           // 0..7
    const int h = lane >> 5;             // half-wave: edge parity
    const int j = lane & 31;             // feature-pair index (24..31 = pad lanes)
    const bool act = (j < NPAIR);
    const int ja = act ? j : 0;          // inactive lanes alias lane-0's word
    float bb0 = 0.0f, bb1 = 0.0f;
    if (act) { bb0 = bias[2 * j]; bb1 = bias[2 * j + 1]; }
    const int rbase = b * RB;
    for (int ri = wave; ri < RB; ri += 16) {    // dual rows: ri and ri+8
        const int riA = ri, riB = ri + 8;       // riB < RB always (RB=128)
        const int rA = rbase + riA, rB = rbase + riB;
        float a0A = 0.0f, a1A = 0.0f, a0B = 0.0f, a1B = 0.0f;
        if (sorted) {
            int keA = lrp[riA + 1], keB = lrp[riB + 1];
            int kA = lrp[riA] + h, kB = lrp[riB] + h;
            // combined phase: 8 real independent line loads in flight
            while (kA < keA && kB < keB) {
                GATHER4(kA, keA, a0A, a1A)
                GATHER4(kB, keB, a0B, a1B)
                kA += 8; kB += 8;
            }
            for (; kA < keA; kA += 8) GATHER4(kA, keA, a0A, a1A)
            for (; kB < keB; kB += 8) GATHER4(kB, keB, a0B, a1B)
        } else {                         // overflow fallback (statistically unreachable)
            for (int e = s; e < t; e++) {
                unsigned rc = binned[e];
                int rr = (int)(rc >> RSH);
                if (h == 0 && act && (rr == riA || rr == riB)) {
                    unsigned u0 = zp[((size_t)(rc & CMASK) << 5) + ja];
                    if (rr == riA) {
                        a0A += __uint_as_float(u0 << 16);
                        a1A += __uint_as_float(u0 & 0xffff0000u);
                    } else {
                        a0B += __uint_as_float(u0 << 16);
                        a1B += __uint_as_float(u0 & 0xffff0000u);
                    }
                }
            }
        }
        a0A += __shfl_xor(a0A, 32, 64);  // combine edge parities
        a1A += __shfl_xor(a1A, 32, 64);
        a0B += __shfl_xor(a0B, 32, 64);
        a1B += __shfl_xor(a1B, 32, 64);
        if (h == 0 && act) {
            if (rA < N) {
                float dr = dis[rA];
                float v0 = dr * a0A + bb0;
                float v1 = dr * a1A + bb1;
                float2 o;
                o.x = v0 > 0.0f ? v0 : 0.0f;
                o.y = v1 > 0.0f ? v1 : 0.0f;
                *(float2*)(out + (size_t)rA * NF + 2 * j) = o;
            }
            if (rB < N) {
                float dr = dis[rB];
                float v0 = dr * a0B + bb0;
                float v1 = dr * a1B + bb1;
                float2 o;
                o.x = v0 > 0.0f ? v0 : 0.0f;
                o.y = v1 > 0.0f ? v1 : 0.0f;
                *(float2*)(out + (size_t)rB * NF + 2 * j) = o;
            }
        }
    }
}

extern "C" void kernel_launch(void* const* d_in, const int* in_sizes, int n_in,
                              void* d_out, int out_size, void* d_ws, size_t ws_size,
                              hipStream_t stream) {
    const float* x    = (const float*)d_in[0];
    const int*   ei   = (const int*)d_in[1];
    const float* W    = (const float*)d_in[2];
    const float* bias = (const float*)d_in[3];
    float* out = (float*)d_out;

    const int N = in_sizes[0] / NF;
    const int E = in_sizes[1] / 2;
    const int* row = ei;                      // edge_index[0]
    const int* col = ei + E;                  // edge_index[1]
    const int NBUK = (N + RB - 1) / RB;       // 782
    const int NCH  = (E + CHUNK - 1) / CHUNK; // 98
    const int SL   = (NBUK + NSPLIT - 1) / NSPLIT;   // bucket-slice length (391)

    // workspace layout
    char* ws = (char*)d_ws;
    unsigned* zp      = (unsigned*)ws;       ws += (size_t)N * ZLD * 4;          // 12.8 MB
    unsigned* binned  = (unsigned*)ws;       ws += (size_t)NBUK * CAP * 4;       // 12.8 MB
    float*    dis     = (float*)ws;          ws += (size_t)N * 4;
    int*      blkhist = (int*)ws;            ws += (size_t)NCH * NBUK * 4;       // 306 KB
    int*      btotal  = (int*)ws;            ws += (size_t)NBUK * 4;
    int*      lrp_g   = (int*)ws;            ws += (size_t)NBUK * (RB + 1) * 4;  // 403 KB

    histA_kernel<<<NCH * NSPLIT, 512, SL * 4, stream>>>(row, blkhist, NBUK, SL, E);
    scanB1_kernel<<<NBUK, 64, 0, stream>>>(blkhist, btotal, NBUK, NCH);
    scatC_kernel<<<NCH * NSPLIT, 512, SL * 4, stream>>>(row, col, blkhist, binned,
                                                        NBUK, SL, E);
    distrans_kernel<<<NBUK, 512, 0, stream>>>(btotal, binned, x, W, dis, lrp_g,
                                              (unsigned short*)zp, N);
    aggregate_kernel<<<NBUK, 512, 0, stream>>>(btotal, binned, lrp_g, zp, dis, bias, out, N);
}